// Round 2
// baseline (127.833 us; speedup 1.0000x reference)
//
#include <hip/hip_runtime.h>
#include <hip/hip_bf16.h>

typedef short bf16x8 __attribute__((ext_vector_type(8)));
typedef float f32x4 __attribute__((ext_vector_type(4)));
typedef unsigned short u16;

#define B_    32
#define L_    8192
#define C_    8
#define P_    512
#define PL_   64
#define PC_   4
#define CED_  8
#define SED_  16
#define D_    256
#define INDIM 2576
#define NROWS (B_ * P_) // 16384

// tabF vector slots (each 256 f32)
#define TB_WTS 0
#define TB_IWT 1
#define TB_SYS 2
#define TB_GW1 3
#define TB_BWB 4
#define TB_CH0 5   // ..9
#define TB_W2G 10
#define TB_B2  11

__device__ __forceinline__ u16 f2bf(float f) {
    __hip_bfloat16 h = __float2bfloat16(f);
    return *reinterpret_cast<u16*>(&h);
}
__device__ __forceinline__ float bf2f(u16 u) {
    __hip_bfloat16 h = *reinterpret_cast<__hip_bfloat16*>(&u);
    return __bfloat162float(h);
}

// ================================================================= prep
// Builds: wdt[n][k] = bf16(g1[k]*W1[k,n]) for k<256 (data block, B^T layout)
//         w2t[n][k] = bf16(g2[k]*W2[k,n])
//         tabF vectors: Wtsum, iWt, sysW (direct); gW1sum, bW1b1, chW[5] (via partials)
//                       W2gsum, bias2 (direct)
//         scal[12]: cesum[5], cesumsq[5], sesum, sesumsq
__global__ __launch_bounds__(256) void k_prep(
    const float* __restrict__ W1, const float* __restrict__ W2,
    const float* __restrict__ g1, const float* __restrict__ bb1,
    const float* __restrict__ g2, const float* __restrict__ bb2,
    const float* __restrict__ b2,
    const float* __restrict__ ce, const float* __restrict__ se,
    const int* __restrict__ ctm, const int* __restrict__ sysid,
    u16* __restrict__ wdt, u16* __restrict__ w2t, float* __restrict__ tabF,
    float* __restrict__ scal, float* __restrict__ pGW, float* __restrict__ pBW,
    float* __restrict__ pCH)
{
    int kb = blockIdx.x;
    int n = threadIdx.x;
    int sid = sysid[0];
    __shared__ float cef[5][32];
    __shared__ float sv[176], sqv[176];

    if (kb < 11) {
        bool chb = (kb >= 2 && kb <= 9);
        if (chb) {
            if (n < 160) {
                int s5 = n >> 5, s = n & 31;
                cef[s5][s] = ce[ctm[sid * 20 + s5 + (s >> 3)] * CED_ + (s & 7)];
            }
            __syncthreads();
        }
        float pg = 0.f, pb = 0.f, pwts = 0.f, piwt = 0.f, psys = 0.f;
        float pch0 = 0, pch1 = 0, pch2 = 0, pch3 = 0, pch4 = 0;
        int kbase = kb * 256;
        int kend = INDIM - kbase; if (kend > 256) kend = 256;
        for (int kt = 0; kt < kend; ++kt) {
            int k = kbase + kt;
            float wv = W1[k * D_ + n];
            float gw = g1[k] * wv;
            pg += gw; pb += bb1[k] * wv;
            if (kb == 0) {
                wdt[n * 256 + k] = f2bf(gw);
            } else if (kb == 1) {
                float fi = (float)(kt >> 2);
                pwts += gw; piwt += fi * gw;
            } else if (chb) {
                int s = k & 31;
                pch0 += cef[0][s] * gw; pch1 += cef[1][s] * gw; pch2 += cef[2][s] * gw;
                pch3 += cef[3][s] * gw; pch4 += cef[4][s] * gw;
            } else { // kb==10 : sys block
                psys += se[sid * SED_ + (k - 2560)] * gw;
            }
        }
        pGW[kb * 256 + n] = pg; pBW[kb * 256 + n] = pb;
        if (kb == 1) { tabF[TB_WTS * 256 + n] = pwts; tabF[TB_IWT * 256 + n] = piwt; }
        if (chb) {
            int p = kb - 2;
            pCH[(p * 5 + 0) * 256 + n] = pch0;
            pCH[(p * 5 + 1) * 256 + n] = pch1;
            pCH[(p * 5 + 2) * 256 + n] = pch2;
            pCH[(p * 5 + 3) * 256 + n] = pch3;
            pCH[(p * 5 + 4) * 256 + n] = pch4;
        }
        if (kb == 10) tabF[TB_SYS * 256 + n] = psys;
    } else if (kb == 11) {
        float p2g = 0, p2b = 0;
        for (int kt = 0; kt < 256; ++kt) {
            float wv = W2[kt * D_ + n];
            float gw = g2[kt] * wv;
            p2g += gw; p2b += bb2[kt] * wv;
            w2t[n * 256 + kt] = f2bf(gw);
        }
        tabF[TB_W2G * 256 + n] = p2g;
        tabF[TB_B2  * 256 + n] = p2b + b2[n];
    } else { // kb==12 : scalars
        if (n < 160) {
            int s5 = n >> 5, s = n & 31;
            float v = ce[ctm[sid * 20 + s5 + (s >> 3)] * CED_ + (s & 7)];
            sv[n] = v; sqv[n] = v * v;
        } else if (n < 176) {
            float v = se[sid * SED_ + (n - 160)];
            sv[n] = v; sqv[n] = v * v;
        }
        __syncthreads();
        if (n < 5) {
            float a = 0, bq = 0;
            for (int j2 = 0; j2 < 32; ++j2) { a += sv[n * 32 + j2]; bq += sqv[n * 32 + j2]; }
            scal[n] = a; scal[5 + n] = bq;
        }
        if (n == 10) {
            float a = 0, bq = 0;
            for (int j2 = 0; j2 < 16; ++j2) { a += sv[160 + j2]; bq += sqv[160 + j2]; }
            scal[10] = a; scal[11] = bq;
        }
        if (n >= 12 && n < 16) scal[n] = 0.f;
    }
}

__global__ __launch_bounds__(256) void k_reduce(
    const float* __restrict__ pGW, const float* __restrict__ pBW,
    const float* __restrict__ pCH, const float* __restrict__ b1,
    float* __restrict__ tabF)
{
    int n = threadIdx.x;
    float a = 0, bq = 0;
    for (int p = 0; p < 11; ++p) { a += pGW[p * 256 + n]; bq += pBW[p * 256 + n]; }
    tabF[TB_GW1 * 256 + n] = a;
    tabF[TB_BWB * 256 + n] = bq + b1[n];
    for (int s5 = 0; s5 < 5; ++s5) {
        float c = 0;
        for (int p = 0; p < 8; ++p) c += pCH[(p * 5 + s5) * 256 + n];
        tabF[(TB_CH0 + s5) * 256 + n] = c;
    }
}

// ================================================================= main fused
// 64 rows/block, 512 threads (8 waves), grid 256.
// Phases: tab-stage | gather+LN1 stats | GEMM1(K=256)+fold+SiLU -> Hs |
//         LN2 stats | GEMM2(K=256)+fold -> out
__global__ __launch_bounds__(512, 2) void k_main(
    const float* __restrict__ x, const float* __restrict__ fs,
    const int* __restrict__ sLp, const int* __restrict__ sCp,
    const u16* __restrict__ wdt, const u16* __restrict__ w2t,
    const float* __restrict__ tabF, const float* __restrict__ scal,
    float* __restrict__ out)
{
    // chunked [8][64][40] bf16 tiles (m97-style pitch-40, 80B = 5x16B rows)
    __shared__ __attribute__((aligned(16))) u16 As[8 * 64 * 40];
    __shared__ __attribute__((aligned(16))) u16 Hs[8 * 64 * 40];
    __shared__ float tb[12 * 256];
    __shared__ float sc[16];
    __shared__ float ps1[512], ps2[512];
    __shared__ float rmu[64], rrs[64], rsl[64];
    __shared__ int   rsc[64];
    __shared__ float rmu2[64], rrs2[64];

    int t = threadIdx.x;
    int r0 = blockIdx.x * 64;
    int b = r0 >> 9;                 // uniform per block (64 | 512)
    float fsinv = 1.0f / fs[b];

    // ---- phase 0: stage epilogue tables
    for (int i = t; i < 12 * 256; i += 512) tb[i] = tabF[i];
    if (t < 16) sc[t] = scal[t];

    // ---- phase 1: gather data patch + LN1 stats
    int row = t >> 3, u = t & 7;
    int r = r0 + row;
    int sL = sLp[r], sC = sCp[r];
    {
        const float* xb = x + ((size_t)b << 16);   // b * 8192 * 8
        float s = 0.f, sq = 0.f;
#pragma unroll
        for (int i2 = 0; i2 < 8; ++i2) {
            int i = i2 * 8 + u;
            const float* px = xb + (size_t)(sL + i) * 8 + sC;
            float v0 = px[0], v1 = px[1], v2 = px[2], v3 = px[3];
            s += v0 + v1 + v2 + v3;
            sq += v0 * v0 + v1 * v1 + v2 * v2 + v3 * v3;
            int k = i * 4;                    // 4 consecutive, 4-aligned
            *(ushort4*)&As[(k >> 5) * 2560 + row * 40 + (k & 31)] =
                make_ushort4(f2bf(v0), f2bf(v1), f2bf(v2), f2bf(v3));
        }
        ps1[t] = s; ps2[t] = sq;
    }
    __syncthreads();
    if (u == 0) {
        float ds = 0, dq = 0;
        for (int q = 0; q < 8; ++q) { ds += ps1[row * 8 + q]; dq += ps2[row * 8 + q]; }
        float sLf = (float)sL;
        float Ss = ds + 4.f * fsinv * (64.f * sLf + 2016.f) + 64.f * sc[sC] + sc[10];
        float Sq = dq + 4.f * fsinv * fsinv * (64.f * sLf * sLf + 4032.f * sLf + 85344.f)
                 + 64.f * sc[5 + sC] + sc[11];
        float mu = Ss * (1.f / (float)INDIM);
        float var = Sq * (1.f / (float)INDIM) - mu * mu;
        rmu[row] = mu; rrs[row] = rsqrtf(var + 1e-5f);
        rsl[row] = sLf; rsc[row] = sC;
    }
    __syncthreads();

    // ---- phase 2: GEMM1 (K=256) + LN1-fold + SiLU
    int w = t >> 6, lane = t & 63, l15 = lane & 15, hi = lane >> 4;
    int col0 = w * 32;
    {
        f32x4 acc[4][2];
#pragma unroll
        for (int fm = 0; fm < 4; ++fm)
#pragma unroll
            for (int fn = 0; fn < 2; ++fn) acc[fm][fn] = (f32x4){0.f, 0.f, 0.f, 0.f};
#pragma unroll
        for (int kk = 0; kk < 8; ++kk) {
            bf16x8 a0 = *(const bf16x8*)&As[kk * 2560 + (l15     ) * 40 + hi * 8];
            bf16x8 a1 = *(const bf16x8*)&As[kk * 2560 + (16 + l15) * 40 + hi * 8];
            bf16x8 a2 = *(const bf16x8*)&As[kk * 2560 + (32 + l15) * 40 + hi * 8];
            bf16x8 a3 = *(const bf16x8*)&As[kk * 2560 + (48 + l15) * 40 + hi * 8];
#pragma unroll
            for (int fn = 0; fn < 2; ++fn) {
                bf16x8 bv = *(const bf16x8*)&wdt[(col0 + fn * 16 + l15) * 256 + kk * 32 + hi * 8];
                acc[0][fn] = __builtin_amdgcn_mfma_f32_16x16x32_bf16(a0, bv, acc[0][fn], 0, 0, 0);
                acc[1][fn] = __builtin_amdgcn_mfma_f32_16x16x32_bf16(a1, bv, acc[1][fn], 0, 0, 0);
                acc[2][fn] = __builtin_amdgcn_mfma_f32_16x16x32_bf16(a2, bv, acc[2][fn], 0, 0, 0);
                acc[3][fn] = __builtin_amdgcn_mfma_f32_16x16x32_bf16(a3, bv, acc[3][fn], 0, 0, 0);
            }
        }
        const float* tWTS = &tb[TB_WTS * 256];
        const float* tIWT = &tb[TB_IWT * 256];
        const float* tSYS = &tb[TB_SYS * 256];
        const float* tGW1 = &tb[TB_GW1 * 256];
        const float* tBWB = &tb[TB_BWB * 256];
        const float* tCH  = &tb[TB_CH0 * 256];
#pragma unroll
        for (int fm = 0; fm < 4; ++fm)
#pragma unroll
            for (int fn = 0; fn < 2; ++fn)
#pragma unroll
                for (int j = 0; j < 4; ++j) {
                    int rr = fm * 16 + hi * 4 + j;
                    int col = col0 + fn * 16 + l15;
                    float mu = rmu[rr], rs = rrs[rr], sLf = rsl[rr];
                    int sCc = rsc[rr];
                    float fw = acc[fm][fn][j]
                             + fsinv * (sLf * tWTS[col] + tIWT[col])
                             + tCH[sCc * 256 + col] + tSYS[col];
                    float o1 = rs * (fw - mu * tGW1[col]) + tBWB[col];
                    float h = o1 / (1.f + __expf(-o1));          // SiLU
                    Hs[(col >> 5) * 2560 + rr * 40 + (col & 31)] = f2bf(h);
                }
    }
    __syncthreads();

    // ---- phase 3: LN2 stats from Hs
    {
        float s2 = 0.f, q2 = 0.f;
        const u16* hp = &Hs[u * 2560 + row * 40];
#pragma unroll
        for (int q = 0; q < 4; ++q) {
            bf16x8 hv = *(const bf16x8*)(hp + q * 8);
#pragma unroll
            for (int e = 0; e < 8; ++e) {
                float f = bf2f((u16)hv[e]);
                s2 += f; q2 += f * f;
            }
        }
        ps1[t] = s2; ps2[t] = q2;
    }
    __syncthreads();
    if (u == 0) {
        float ts = 0, tq = 0;
        for (int q = 0; q < 8; ++q) { ts += ps1[row * 8 + q]; tq += ps2[row * 8 + q]; }
        float mu2 = ts * (1.f / 256.f);
        float var2 = tq * (1.f / 256.f) - mu2 * mu2;
        rmu2[row] = mu2; rrs2[row] = rsqrtf(var2 + 1e-5f);
    }
    __syncthreads();

    // ---- phase 4: GEMM2 (K=256) + LN2-fold -> out
    {
        f32x4 acc[4][2];
#pragma unroll
        for (int fm = 0; fm < 4; ++fm)
#pragma unroll
            for (int fn = 0; fn < 2; ++fn) acc[fm][fn] = (f32x4){0.f, 0.f, 0.f, 0.f};
#pragma unroll
        for (int kk = 0; kk < 8; ++kk) {
            bf16x8 a0 = *(const bf16x8*)&Hs[kk * 2560 + (l15     ) * 40 + hi * 8];
            bf16x8 a1 = *(const bf16x8*)&Hs[kk * 2560 + (16 + l15) * 40 + hi * 8];
            bf16x8 a2 = *(const bf16x8*)&Hs[kk * 2560 + (32 + l15) * 40 + hi * 8];
            bf16x8 a3 = *(const bf16x8*)&Hs[kk * 2560 + (48 + l15) * 40 + hi * 8];
#pragma unroll
            for (int fn = 0; fn < 2; ++fn) {
                bf16x8 bv = *(const bf16x8*)&w2t[(col0 + fn * 16 + l15) * 256 + kk * 32 + hi * 8];
                acc[0][fn] = __builtin_amdgcn_mfma_f32_16x16x32_bf16(a0, bv, acc[0][fn], 0, 0, 0);
                acc[1][fn] = __builtin_amdgcn_mfma_f32_16x16x32_bf16(a1, bv, acc[1][fn], 0, 0, 0);
                acc[2][fn] = __builtin_amdgcn_mfma_f32_16x16x32_bf16(a2, bv, acc[2][fn], 0, 0, 0);
                acc[3][fn] = __builtin_amdgcn_mfma_f32_16x16x32_bf16(a3, bv, acc[3][fn], 0, 0, 0);
            }
        }
        const float* tW2G = &tb[TB_W2G * 256];
        const float* tB2  = &tb[TB_B2  * 256];
#pragma unroll
        for (int fm = 0; fm < 4; ++fm)
#pragma unroll
            for (int fn = 0; fn < 2; ++fn)
#pragma unroll
                for (int j = 0; j < 4; ++j) {
                    int rr = fm * 16 + hi * 4 + j;
                    int col = col0 + fn * 16 + l15;
                    float o = rrs2[rr] * (acc[fm][fn][j] - rmu2[rr] * tW2G[col]) + tB2[col];
                    out[(size_t)(r0 + rr) * 256 + col] = o;
                }
    }
}

// ================================================================= launch
extern "C" void kernel_launch(void* const* d_in, const int* in_sizes, int n_in,
                              void* d_out, int out_size, void* d_ws, size_t ws_size,
                              hipStream_t stream) {
    const float* x   = (const float*)d_in[0];
    const float* fs  = (const float*)d_in[1];
    const float* ce  = (const float*)d_in[2];
    const float* se  = (const float*)d_in[3];
    const float* g1  = (const float*)d_in[4];
    const float* bb1 = (const float*)d_in[5];
    const float* W1  = (const float*)d_in[6];
    const float* b1  = (const float*)d_in[7];
    const float* g2  = (const float*)d_in[8];
    const float* bb2 = (const float*)d_in[9];
    const float* W2  = (const float*)d_in[10];
    const float* b2  = (const float*)d_in[11];
    const int* sL    = (const int*)d_in[12];
    const int* sC    = (const int*)d_in[13];
    const int* ctm   = (const int*)d_in[14];
    const int* sysid = (const int*)d_in[15];
    float* out = (float*)d_out;

    char* ws = (char*)d_ws;
    u16*   wdt  = (u16*)(ws + 0);          // 131072 B
    u16*   w2t  = (u16*)(ws + 131072);     // 131072 B
    float* tabF = (float*)(ws + 262144);   // 12288 B
    float* scal = (float*)(ws + 274432);   // 64 B
    float* pGW  = (float*)(ws + 274496);   // 11264 B
    float* pBW  = (float*)(ws + 285760);   // 11264 B
    float* pCH  = (float*)(ws + 297024);   // 40960 B

    k_prep<<<dim3(13), dim3(256), 0, stream>>>(
        W1, W2, g1, bb1, g2, bb2, b2, ce, se, ctm, sysid,
        wdt, w2t, tabF, scal, pGW, pBW, pCH);
    k_reduce<<<dim3(1), dim3(256), 0, stream>>>(pGW, pBW, pCH, b1, tabF);
    k_main<<<dim3(NROWS / 64), dim3(512), 0, stream>>>(
        x, fs, sL, sC, wdt, w2t, tabF, scal, out);
}

// Round 3
// 47.537 us; speedup vs baseline: 2.6891x; 2.6891x over previous
//
#include <hip/hip_runtime.h>
#include <hip/hip_bf16.h>

typedef short bf16x8 __attribute__((ext_vector_type(8)));
typedef float f32x4 __attribute__((ext_vector_type(4)));
typedef unsigned short u16;

#define B_    32
#define L_    8192
#define C_    8
#define P_    512
#define PL_   64
#define PC_   4
#define CED_  8
#define SED_  16
#define D_    256
#define INDIM 2576
#define NROWS (B_ * P_) // 16384
#define NCH_W1 161      // 2576 / 16
#define NCH_W2 16       // 256 / 16

// tabF vector slots (each 256 f32)
#define TB_WTS 0
#define TB_IWT 1
#define TB_SYS 2
#define TB_GW1 3
#define TB_BWB 4
#define TB_CH0 5   // ..9
#define TB_W2G 10
#define TB_B2  11

__device__ __forceinline__ u16 f2bf(float f) {
    __hip_bfloat16 h = __float2bfloat16(f);
    return *reinterpret_cast<u16*>(&h);
}
__device__ __forceinline__ float bf2f(u16 u) {
    __hip_bfloat16 h = *reinterpret_cast<__hip_bfloat16*>(&u);
    return __bfloat162float(h);
}

// ================================================================= prep stage 1
// Per 16-row k-chunk partial dot products of W1 columns with 10 coefficient
// vectors. Chunks never straddle feature-block boundaries (256,512,2560 all
// multiples of 16). Blocks 161..176 handle W2 (g2-scaled column sums).
__global__ __launch_bounds__(256) void k_part(
    const float* __restrict__ W1, const float* __restrict__ W2,
    const float* __restrict__ g1, const float* __restrict__ bb1,
    const float* __restrict__ g2, const float* __restrict__ bb2,
    const float* __restrict__ ce, const float* __restrict__ se,
    const int* __restrict__ ctm, const int* __restrict__ sysid,
    float* __restrict__ part, float* __restrict__ part2)
{
    int c = blockIdx.x;
    int n = threadIdx.x;
    int sid = sysid[0];
    __shared__ float sg[16], sb[16], st[16], cs5[5][16];

    if (c < NCH_W1) {
        int k0 = c * 16;
        int type = (k0 < 256) ? 0 : (k0 < 512) ? 1 : (k0 < 2560) ? 2 : 3;
        if (n < 16) {
            int k = k0 + n;
            sg[n] = g1[k]; sb[n] = bb1[k];
            float xv = 0.f;
            if (type == 1) xv = (float)((k - 256) >> 2);
            if (type == 3) xv = se[sid * SED_ + n];
            st[n] = xv;
        }
        if (type == 2 && n < 80) {
            int s = n >> 4, kt = n & 15, k = k0 + kt;
            cs5[s][kt] = ce[ctm[sid * 20 + s + ((k >> 3) & 3)] * CED_ + (k & 7)];
        }
        __syncthreads();
        float pg = 0, pb = 0, a2 = 0, a3 = 0, a4 = 0;
        float a5 = 0, a6 = 0, a7 = 0, a8 = 0, a9 = 0;
#pragma unroll
        for (int kt = 0; kt < 16; ++kt) {
            float wv = W1[(size_t)(k0 + kt) * D_ + n];
            float gw = sg[kt] * wv;
            pg += gw; pb += sb[kt] * wv;
            if (type == 1) { a2 += gw; a3 += st[kt] * gw; }
            if (type == 2) {
                a5 += cs5[0][kt] * gw; a6 += cs5[1][kt] * gw; a7 += cs5[2][kt] * gw;
                a8 += cs5[3][kt] * gw; a9 += cs5[4][kt] * gw;
            }
            if (type == 3) a4 += st[kt] * gw;
        }
        float outs[10] = {pg, pb, a2, a3, a4, a5, a6, a7, a8, a9};
#pragma unroll
        for (int j = 0; j < 10; ++j)
            part[(j * NCH_W1 + c) * 256 + n] = outs[j];
    } else {
        int cc = c - NCH_W1;
        int k0 = cc * 16;
        if (n < 16) { sg[n] = g2[k0 + n]; sb[n] = bb2[k0 + n]; }
        __syncthreads();
        float pg = 0, pb = 0;
#pragma unroll
        for (int kt = 0; kt < 16; ++kt) {
            float wv = W2[(size_t)(k0 + kt) * D_ + n];
            pg += sg[kt] * wv; pb += sb[kt] * wv;
        }
        part2[(0 * NCH_W2 + cc) * 256 + n] = pg;
        part2[(1 * NCH_W2 + cc) * 256 + n] = pb;
    }
}

// ================================================================= prep stage 2
// 64x64 tile transposes: wdt[n][k]=bf16(g1[k]*W1[k,n]) (k<256), w2t likewise.
__global__ __launch_bounds__(256) void k_tr(
    const float* __restrict__ W1, const float* __restrict__ W2,
    const float* __restrict__ g1, const float* __restrict__ g2,
    u16* __restrict__ wdt, u16* __restrict__ w2t)
{
    __shared__ u16 tileT[64][65];
    int blk = blockIdx.x;
    const float* W = (blk < 16) ? W1 : W2;
    const float* g = (blk < 16) ? g1 : g2;
    u16* dst = (blk < 16) ? wdt : w2t;
    int bb = blk & 15;
    int tr = (bb >> 2) * 64;   // k base
    int tc = (bb & 3) * 64;    // n base
    int t = threadIdx.x;
    int rr = t >> 2, cc = (t & 3) * 16;
    float gs = g[tr + rr];
    const float* src = W + (size_t)(tr + rr) * D_ + tc + cc;
#pragma unroll
    for (int j = 0; j < 16; ++j)
        tileT[cc + j][rr] = f2bf(gs * src[j]);
    __syncthreads();
    int nn = t >> 2, kb = (t & 3) * 16;
    u16* dp = dst + (size_t)(tc + nn) * 256 + tr + kb;
#pragma unroll
    for (int j = 0; j < 16; ++j)
        dp[j] = tileT[nn][kb + j];
}

// ================================================================= prep stage 3
// Reduce partials into tabF; W2 sums; scalar sums.
__global__ __launch_bounds__(1024) void k_fin(
    const float* __restrict__ part, const float* __restrict__ part2,
    const float* __restrict__ b1, const float* __restrict__ b2,
    const float* __restrict__ ce, const float* __restrict__ se,
    const int* __restrict__ ctm, const int* __restrict__ sysid,
    float* __restrict__ tabF, float* __restrict__ scal)
{
    __shared__ float red[4][256], red2[4][256];
    __shared__ float sv[176], sqv[176];
    int j = blockIdx.x;
    int t = threadIdx.x, q = t >> 8, n = t & 255;
    if (j < 10) {
        float a = 0;
        for (int c = q; c < NCH_W1; c += 4) a += part[(j * NCH_W1 + c) * 256 + n];
        red[q][n] = a;
        __syncthreads();
        if (q == 0) {
            float s = red[0][n] + red[1][n] + red[2][n] + red[3][n];
            const int slotmap[10] = {TB_GW1, TB_BWB, TB_WTS, TB_IWT, TB_SYS,
                                     TB_CH0, TB_CH0 + 1, TB_CH0 + 2, TB_CH0 + 3, TB_CH0 + 4};
            if (j == 1) s += b1[n];
            tabF[slotmap[j] * 256 + n] = s;
        }
    } else {
        int sid = sysid[0];
        float a0 = 0, a1 = 0;
        for (int c = q; c < NCH_W2; c += 4) {
            a0 += part2[(0 * NCH_W2 + c) * 256 + n];
            a1 += part2[(1 * NCH_W2 + c) * 256 + n];
        }
        red[q][n] = a0; red2[q][n] = a1;
        if (t < 160) {
            int s5 = t >> 5, s = t & 31;
            float v = ce[ctm[sid * 20 + s5 + (s >> 3)] * CED_ + (s & 7)];
            sv[t] = v; sqv[t] = v * v;
        } else if (t < 176) {
            float v = se[sid * SED_ + (t - 160)];
            sv[t] = v; sqv[t] = v * v;
        }
        __syncthreads();
        if (q == 0) {
            tabF[TB_W2G * 256 + n] = red[0][n] + red[1][n] + red[2][n] + red[3][n];
            tabF[TB_B2  * 256 + n] = red2[0][n] + red2[1][n] + red2[2][n] + red2[3][n] + b2[n];
        }
        if (t < 5) {
            float a = 0, bq = 0;
            for (int j2 = 0; j2 < 32; ++j2) { a += sv[t * 32 + j2]; bq += sqv[t * 32 + j2]; }
            scal[t] = a; scal[5 + t] = bq;
        }
        if (t == 10) {
            float a = 0, bq = 0;
            for (int j2 = 0; j2 < 16; ++j2) { a += sv[160 + j2]; bq += sqv[160 + j2]; }
            scal[10] = a; scal[11] = bq;
        }
        if (t >= 12 && t < 16) scal[t] = 0.f;
    }
}

// ================================================================= main fused
// 64 rows/block, 512 threads (8 waves), grid 256.
__global__ __launch_bounds__(512, 2) void k_main(
    const float* __restrict__ x, const float* __restrict__ fs,
    const int* __restrict__ sLp, const int* __restrict__ sCp,
    const u16* __restrict__ wdt, const u16* __restrict__ w2t,
    const float* __restrict__ tabF, const float* __restrict__ scal,
    float* __restrict__ out)
{
    __shared__ __attribute__((aligned(16))) u16 As[8 * 64 * 40];
    __shared__ __attribute__((aligned(16))) u16 Hs[8 * 64 * 40];
    __shared__ float tb[12 * 256];
    __shared__ float sc[16];
    __shared__ float ps1[512], ps2[512];
    __shared__ float rmu[64], rrs[64], rsl[64];
    __shared__ int   rsc[64];
    __shared__ float rmu2[64], rrs2[64];

    int t = threadIdx.x;
    int r0 = blockIdx.x * 64;
    int b = r0 >> 9;
    float fsinv = 1.0f / fs[b];

    for (int i = t; i < 12 * 256; i += 512) tb[i] = tabF[i];
    if (t < 16) sc[t] = scal[t];

    int row = t >> 3, u = t & 7;
    int r = r0 + row;
    int sL = sLp[r], sC = sCp[r];
    {
        const float* xb = x + ((size_t)b << 16);
        float s = 0.f, sq = 0.f;
#pragma unroll
        for (int i2 = 0; i2 < 8; ++i2) {
            int i = i2 * 8 + u;
            const float* px = xb + (size_t)(sL + i) * 8 + sC;
            float v0 = px[0], v1 = px[1], v2 = px[2], v3 = px[3];
            s += v0 + v1 + v2 + v3;
            sq += v0 * v0 + v1 * v1 + v2 * v2 + v3 * v3;
            int k = i * 4;
            *(ushort4*)&As[(k >> 5) * 2560 + row * 40 + (k & 31)] =
                make_ushort4(f2bf(v0), f2bf(v1), f2bf(v2), f2bf(v3));
        }
        ps1[t] = s; ps2[t] = sq;
    }
    __syncthreads();
    if (u == 0) {
        float ds = 0, dq = 0;
        for (int q = 0; q < 8; ++q) { ds += ps1[row * 8 + q]; dq += ps2[row * 8 + q]; }
        float sLf = (float)sL;
        float Ss = ds + 4.f * fsinv * (64.f * sLf + 2016.f) + 64.f * sc[sC] + sc[10];
        float Sq = dq + 4.f * fsinv * fsinv * (64.f * sLf * sLf + 4032.f * sLf + 85344.f)
                 + 64.f * sc[5 + sC] + sc[11];
        float mu = Ss * (1.f / (float)INDIM);
        float var = Sq * (1.f / (float)INDIM) - mu * mu;
        rmu[row] = mu; rrs[row] = rsqrtf(var + 1e-5f);
        rsl[row] = sLf; rsc[row] = sC;
    }
    __syncthreads();

    int w = t >> 6, lane = t & 63, l15 = lane & 15, hi = lane >> 4;
    int col0 = w * 32;
    {
        f32x4 acc[4][2];
#pragma unroll
        for (int fm = 0; fm < 4; ++fm)
#pragma unroll
            for (int fn = 0; fn < 2; ++fn) acc[fm][fn] = (f32x4){0.f, 0.f, 0.f, 0.f};
#pragma unroll
        for (int kk = 0; kk < 8; ++kk) {
            bf16x8 a0 = *(const bf16x8*)&As[kk * 2560 + (l15     ) * 40 + hi * 8];
            bf16x8 a1 = *(const bf16x8*)&As[kk * 2560 + (16 + l15) * 40 + hi * 8];
            bf16x8 a2 = *(const bf16x8*)&As[kk * 2560 + (32 + l15) * 40 + hi * 8];
            bf16x8 a3 = *(const bf16x8*)&As[kk * 2560 + (48 + l15) * 40 + hi * 8];
#pragma unroll
            for (int fn = 0; fn < 2; ++fn) {
                bf16x8 bv = *(const bf16x8*)&wdt[(col0 + fn * 16 + l15) * 256 + kk * 32 + hi * 8];
                acc[0][fn] = __builtin_amdgcn_mfma_f32_16x16x32_bf16(a0, bv, acc[0][fn], 0, 0, 0);
                acc[1][fn] = __builtin_amdgcn_mfma_f32_16x16x32_bf16(a1, bv, acc[1][fn], 0, 0, 0);
                acc[2][fn] = __builtin_amdgcn_mfma_f32_16x16x32_bf16(a2, bv, acc[2][fn], 0, 0, 0);
                acc[3][fn] = __builtin_amdgcn_mfma_f32_16x16x32_bf16(a3, bv, acc[3][fn], 0, 0, 0);
            }
        }
        const float* tWTS = &tb[TB_WTS * 256];
        const float* tIWT = &tb[TB_IWT * 256];
        const float* tSYS = &tb[TB_SYS * 256];
        const float* tGW1 = &tb[TB_GW1 * 256];
        const float* tBWB = &tb[TB_BWB * 256];
        const float* tCH  = &tb[TB_CH0 * 256];
#pragma unroll
        for (int fm = 0; fm < 4; ++fm)
#pragma unroll
            for (int fn = 0; fn < 2; ++fn)
#pragma unroll
                for (int j = 0; j < 4; ++j) {
                    int rr = fm * 16 + hi * 4 + j;
                    int col = col0 + fn * 16 + l15;
                    float mu = rmu[rr], rs = rrs[rr], sLf = rsl[rr];
                    int sCc = rsc[rr];
                    float fw = acc[fm][fn][j]
                             + fsinv * (sLf * tWTS[col] + tIWT[col])
                             + tCH[sCc * 256 + col] + tSYS[col];
                    float o1 = rs * (fw - mu * tGW1[col]) + tBWB[col];
                    float h = o1 / (1.f + __expf(-o1));
                    Hs[(col >> 5) * 2560 + rr * 40 + (col & 31)] = f2bf(h);
                }
    }
    __syncthreads();

    {
        float s2 = 0.f, q2 = 0.f;
        const u16* hp = &Hs[u * 2560 + row * 40];
#pragma unroll
        for (int q = 0; q < 4; ++q) {
            bf16x8 hv = *(const bf16x8*)(hp + q * 8);
#pragma unroll
            for (int e = 0; e < 8; ++e) {
                float f = bf2f((u16)hv[e]);
                s2 += f; q2 += f * f;
            }
        }
        ps1[t] = s2; ps2[t] = q2;
    }
    __syncthreads();
    if (u == 0) {
        float ts = 0, tq = 0;
        for (int q = 0; q < 8; ++q) { ts += ps1[row * 8 + q]; tq += ps2[row * 8 + q]; }
        float mu2 = ts * (1.f / 256.f);
        float var2 = tq * (1.f / 256.f) - mu2 * mu2;
        rmu2[row] = mu2; rrs2[row] = rsqrtf(var2 + 1e-5f);
    }
    __syncthreads();

    {
        f32x4 acc[4][2];
#pragma unroll
        for (int fm = 0; fm < 4; ++fm)
#pragma unroll
            for (int fn = 0; fn < 2; ++fn) acc[fm][fn] = (f32x4){0.f, 0.f, 0.f, 0.f};
#pragma unroll
        for (int kk = 0; kk < 8; ++kk) {
            bf16x8 a0 = *(const bf16x8*)&Hs[kk * 2560 + (l15     ) * 40 + hi * 8];
            bf16x8 a1 = *(const bf16x8*)&Hs[kk * 2560 + (16 + l15) * 40 + hi * 8];
            bf16x8 a2 = *(const bf16x8*)&Hs[kk * 2560 + (32 + l15) * 40 + hi * 8];
            bf16x8 a3 = *(const bf16x8*)&Hs[kk * 2560 + (48 + l15) * 40 + hi * 8];
#pragma unroll
            for (int fn = 0; fn < 2; ++fn) {
                bf16x8 bv = *(const bf16x8*)&w2t[(col0 + fn * 16 + l15) * 256 + kk * 32 + hi * 8];
                acc[0][fn] = __builtin_amdgcn_mfma_f32_16x16x32_bf16(a0, bv, acc[0][fn], 0, 0, 0);
                acc[1][fn] = __builtin_amdgcn_mfma_f32_16x16x32_bf16(a1, bv, acc[1][fn], 0, 0, 0);
                acc[2][fn] = __builtin_amdgcn_mfma_f32_16x16x32_bf16(a2, bv, acc[2][fn], 0, 0, 0);
                acc[3][fn] = __builtin_amdgcn_mfma_f32_16x16x32_bf16(a3, bv, acc[3][fn], 0, 0, 0);
            }
        }
        const float* tW2G = &tb[TB_W2G * 256];
        const float* tB2  = &tb[TB_B2  * 256];
#pragma unroll
        for (int fm = 0; fm < 4; ++fm)
#pragma unroll
            for (int fn = 0; fn < 2; ++fn)
#pragma unroll
                for (int j = 0; j < 4; ++j) {
                    int rr = fm * 16 + hi * 4 + j;
                    int col = col0 + fn * 16 + l15;
                    float o = rrs2[rr] * (acc[fm][fn][j] - rmu2[rr] * tW2G[col]) + tB2[col];
                    out[(size_t)(r0 + rr) * 256 + col] = o;
                }
    }
}

// ================================================================= launch
extern "C" void kernel_launch(void* const* d_in, const int* in_sizes, int n_in,
                              void* d_out, int out_size, void* d_ws, size_t ws_size,
                              hipStream_t stream) {
    const float* x   = (const float*)d_in[0];
    const float* fs  = (const float*)d_in[1];
    const float* ce  = (const float*)d_in[2];
    const float* se  = (const float*)d_in[3];
    const float* g1  = (const float*)d_in[4];
    const float* bb1 = (const float*)d_in[5];
    const float* W1  = (const float*)d_in[6];
    const float* b1  = (const float*)d_in[7];
    const float* g2  = (const float*)d_in[8];
    const float* bb2 = (const float*)d_in[9];
    const float* W2  = (const float*)d_in[10];
    const float* b2  = (const float*)d_in[11];
    const int* sL    = (const int*)d_in[12];
    const int* sC    = (const int*)d_in[13];
    const int* ctm   = (const int*)d_in[14];
    const int* sysid = (const int*)d_in[15];
    float* out = (float*)d_out;

    char* ws = (char*)d_ws;
    u16*   wdt   = (u16*)(ws + 0);           // 131072 B
    u16*   w2t   = (u16*)(ws + 131072);      // 131072 B
    float* tabF  = (float*)(ws + 262144);    // 12288 B
    float* scal  = (float*)(ws + 274432);    // 64 B
    float* part  = (float*)(ws + 274496);    // 10*161*256*4 = 1648640 B
    float* part2 = (float*)(ws + 1923136);   // 2*16*256*4 = 32768 B

    k_part<<<dim3(NCH_W1 + NCH_W2), dim3(256), 0, stream>>>(
        W1, W2, g1, bb1, g2, bb2, ce, se, ctm, sysid, part, part2);
    k_tr<<<dim3(32), dim3(256), 0, stream>>>(W1, W2, g1, g2, wdt, w2t);
    k_fin<<<dim3(11), dim3(1024), 0, stream>>>(
        part, part2, b1, b2, ce, se, ctm, sysid, tabF, scal);
    k_main<<<dim3(NROWS / 64), dim3(512), 0, stream>>>(
        x, fs, sL, sC, wdt, w2t, tabF, scal, out);
}